// Round 1
// baseline (685.649 us; speedup 1.0000x reference)
//
#include <hip/hip_runtime.h>

// MoE top-1 + SwiGLU. B=2 S=2048 D=1024 E=4 H=4096.
// Pipeline: router/argmax -> sort tokens by expert (padded segments) ->
// bf16 GEMM1 (x @ w_v, gate/value paired, fused SiLU*v) -> bf16 GEMM2
// (h @ w_proj, scatter rows back to token order).

#define TTOK 4096
#define DIN  1024
#define HDIM 4096
#define H2   8192
#define TPAD 4608
#define LDK  40   // LDS row stride in bf16 elems (32 + 8 pad; 80B => conflict-light, 16B-aligned)

typedef float f32x4 __attribute__((ext_vector_type(4)));
typedef __bf16 bf16x8 __attribute__((ext_vector_type(8)));
typedef unsigned short u16x8 __attribute__((ext_vector_type(8)));
typedef unsigned short u16x4 __attribute__((ext_vector_type(4)));

__device__ __forceinline__ unsigned short f2b(float f) {
  unsigned int u = __builtin_bit_cast(unsigned int, f);
  u += 0x7fffu + ((u >> 16) & 1u);  // RNE
  return (unsigned short)(u >> 16);
}

// ---------------- router: logits argmax + histogram ----------------
__global__ __launch_bounds__(256) void k_router(const float* __restrict__ x,
    const float* __restrict__ wrt, int* __restrict__ eidx,
    int* __restrict__ rank, int* __restrict__ cnt) {
  const int w = threadIdx.x >> 6, lane = threadIdx.x & 63;
  const int t = blockIdx.x * 4 + w;
  const float* xr = x + (size_t)t * DIN;
  const float4* w4 = (const float4*)wrt;  // w_router[k][e], e fastest (E=4)
  float a0 = 0.f, a1 = 0.f, a2 = 0.f, a3 = 0.f;
  for (int k = 0; k < DIN; k += 64) {
    float xv = xr[k + lane];
    float4 ww = w4[k + lane];
    a0 += xv * ww.x; a1 += xv * ww.y; a2 += xv * ww.z; a3 += xv * ww.w;
  }
  #pragma unroll
  for (int off = 32; off; off >>= 1) {
    a0 += __shfl_xor(a0, off); a1 += __shfl_xor(a1, off);
    a2 += __shfl_xor(a2, off); a3 += __shfl_xor(a3, off);
  }
  if (lane == 0) {
    int e = 0; float b = a0;
    if (a1 > b) { b = a1; e = 1; }
    if (a2 > b) { b = a2; e = 2; }
    if (a3 > b) { b = a3; e = 3; }
    eidx[t] = e;
    rank[t] = atomicAdd(&cnt[e], 1);
  }
}

// ---------------- setup: padded segment offsets + M-tile table ----------------
__global__ void k_setup(const int* __restrict__ cnt, int* __restrict__ poff,
                        int* __restrict__ tExp, int* __restrict__ tRow,
                        int* __restrict__ nMt) {
  int p = 0, nm = 0;
  for (int e = 0; e < 4; e++) {
    poff[e] = p;
    int mt = (cnt[e] + 127) >> 7;
    for (int i = 0; i < mt; i++) { tExp[nm] = e; tRow[nm] = p + i * 128; nm++; }
    p += mt * 128;
  }
  poff[4] = p;
  *nMt = nm;
}

// ---------------- scatter: token -> sorted padded slot ----------------
__global__ __launch_bounds__(256) void k_scatter(const int* __restrict__ eidx,
    const int* __restrict__ rank, const int* __restrict__ poff,
    int* __restrict__ perm) {
  const int t = blockIdx.x * 256 + threadIdx.x;
  const int pos = poff[eidx[t]] + rank[t];
  perm[pos] = t;
}

// ---------------- gather x rows to bf16 A matrix (pads -> 0) ----------------
__global__ __launch_bounds__(256) void k_gather(const float* __restrict__ x,
    const int* __restrict__ perm, unsigned short* __restrict__ A) {
  const int r = blockIdx.x;
  const int t = perm[r];
  unsigned short* dst = A + (size_t)r * DIN + threadIdx.x * 4;
  if (t < 0) {
    u16x4 z{0, 0, 0, 0};
    *(u16x4*)dst = z;
  } else {
    float4 v = *(const float4*)(x + (size_t)t * DIN + threadIdx.x * 4);
    u16x4 o{f2b(v.x), f2b(v.y), f2b(v.z), f2b(v.w)};
    *(u16x4*)dst = o;
  }
}

// ---------------- GEMM1: A[128xK] @ w_v -> fused SwiGLU -> h bf16 ----------------
// Per block: 128 rows x 128 gate cols (+ paired 128 value cols at +HDIM).
__global__ __launch_bounds__(256) void k_gemm1(const unsigned short* __restrict__ A,
    const float* __restrict__ wv, unsigned short* __restrict__ Hb,
    const int* __restrict__ tExp, const int* __restrict__ tRow,
    const int* __restrict__ nMt) {
  if ((int)blockIdx.y >= *nMt) return;
  __shared__ __align__(16) unsigned short As[128 * LDK];
  __shared__ __align__(16) unsigned short Bg[128 * LDK];
  __shared__ __align__(16) unsigned short Bv[128 * LDK];
  const int e = tExp[blockIdx.y];
  const int row0 = tRow[blockIdx.y];
  const int n0 = blockIdx.x * 128;
  const int tid = threadIdx.x;
  const int lane = tid & 63;
  const int w = tid >> 6, wr = w >> 1, wc = w & 1;

  f32x4 accg[4][4], accv[4][4];
  #pragma unroll
  for (int i = 0; i < 4; i++)
    #pragma unroll
    for (int j = 0; j < 4; j++) {
      accg[i][j] = f32x4{0.f, 0.f, 0.f, 0.f};
      accv[i][j] = f32x4{0.f, 0.f, 0.f, 0.f};
    }

  // A staging: 2 threads per row, 16 bf16 each (2x b128)
  const int arow = tid >> 1;
  const int ak = (tid & 1) * 16;
  const unsigned short* aSrc = A + (size_t)(row0 + arow) * DIN + ak;
  // B staging: 128 threads per tile (tid<128 gate, >=128 value).
  // thread covers n = bA + 32c (c=0..3), k = bKg*8 + r (r=0..7); writes
  // transposed Bs[n][k] so fragment reads are k-contiguous b128.
  const int t128 = tid & 127;
  const int bA = t128 & 31;
  const int bKg = t128 >> 5;
  const float* bSrc = wv + (size_t)e * DIN * H2 + n0 + (tid < 128 ? 0 : HDIM);
  unsigned short* bDst = (tid < 128) ? Bg : Bv;

  const int krow = (lane >> 4) * 8;
  const int mrow = lane & 15;

  for (int k0 = 0; k0 < DIN; k0 += 32) {
    u16x8 a0 = *(const u16x8*)(aSrc + k0);
    u16x8 a1 = *(const u16x8*)(aSrc + k0 + 8);
    const float* srow = bSrc + (size_t)(k0 + bKg * 8) * H2;
    *(u16x8*)&As[arow * LDK + ak] = a0;
    *(u16x8*)&As[arow * LDK + ak + 8] = a1;
    #pragma unroll
    for (int c = 0; c < 4; c++) {
      const int n = bA + 32 * c;
      const float* s = srow + n;
      u16x8 pk;
      #pragma unroll
      for (int r = 0; r < 8; r++) pk[r] = f2b(s[(size_t)r * H2]);
      *(u16x8*)&bDst[n * LDK + bKg * 8] = pk;
    }
    __syncthreads();
    u16x8 af[4];
    #pragma unroll
    for (int fm = 0; fm < 4; fm++)
      af[fm] = *(const u16x8*)&As[(wr * 64 + fm * 16 + mrow) * LDK + krow];
    #pragma unroll
    for (int fn = 0; fn < 4; fn++) {
      u16x8 bg = *(const u16x8*)&Bg[(wc * 64 + fn * 16 + mrow) * LDK + krow];
      u16x8 bv = *(const u16x8*)&Bv[(wc * 64 + fn * 16 + mrow) * LDK + krow];
      #pragma unroll
      for (int fm = 0; fm < 4; fm++) {
        accg[fm][fn] = __builtin_amdgcn_mfma_f32_16x16x32_bf16(
            __builtin_bit_cast(bf16x8, af[fm]), __builtin_bit_cast(bf16x8, bg),
            accg[fm][fn], 0, 0, 0);
        accv[fm][fn] = __builtin_amdgcn_mfma_f32_16x16x32_bf16(
            __builtin_bit_cast(bf16x8, af[fm]), __builtin_bit_cast(bf16x8, bv),
            accv[fm][fn], 0, 0, 0);
      }
    }
    __syncthreads();
  }
  // epilogue: h = silu(g)*v, store bf16
  #pragma unroll
  for (int fm = 0; fm < 4; fm++) {
    const int rbase = row0 + wr * 64 + fm * 16 + (lane >> 4) * 4;
    #pragma unroll
    for (int fn = 0; fn < 4; fn++) {
      const int col = n0 + wc * 64 + fn * 16 + mrow;
      #pragma unroll
      for (int j = 0; j < 4; j++) {
        float g = accg[fm][fn][j];
        float v = accv[fm][fn][j];
        float h = g / (1.f + __expf(-g)) * v;
        Hb[(size_t)(rbase + j) * HDIM + col] = f2b(h);
      }
    }
  }
}

// ---------------- GEMM2: h @ w_proj -> scatter fp32 out ----------------
__global__ __launch_bounds__(256) void k_gemm2(const unsigned short* __restrict__ Hb,
    const float* __restrict__ wp, float* __restrict__ out,
    const int* __restrict__ tExp, const int* __restrict__ tRow,
    const int* __restrict__ nMt, const int* __restrict__ perm) {
  if ((int)blockIdx.y >= *nMt) return;
  __shared__ __align__(16) unsigned short As[128 * LDK];
  __shared__ __align__(16) unsigned short Bs[128 * LDK];
  const int e = tExp[blockIdx.y];
  const int row0 = tRow[blockIdx.y];
  const int n0 = blockIdx.x * 128;
  const int tid = threadIdx.x;
  const int lane = tid & 63;
  const int w = tid >> 6, wr = w >> 1, wc = w & 1;
  f32x4 acc[4][4];
  #pragma unroll
  for (int i = 0; i < 4; i++)
    #pragma unroll
    for (int j = 0; j < 4; j++) acc[i][j] = f32x4{0.f, 0.f, 0.f, 0.f};

  const int t128 = tid & 127;
  const int bA = t128 & 31, bKg = t128 >> 5;
  const float* bSrc = wp + (size_t)e * HDIM * DIN + n0;
  const unsigned short* aSrc = Hb + (size_t)(row0 + t128) * HDIM;
  const int krow = (lane >> 4) * 8, mrow = lane & 15;

  for (int k0 = 0; k0 < HDIM; k0 += 32) {
    if (tid < 128) {  // A stage: 1 thread/row, 32 bf16 (4x b128)
      #pragma unroll
      for (int q = 0; q < 4; q++) {
        u16x8 v = *(const u16x8*)(aSrc + k0 + q * 8);
        *(u16x8*)&As[t128 * LDK + q * 8] = v;
      }
    } else {  // B stage (transpose + cvt), same pattern as GEMM1
      const float* srow = bSrc + (size_t)(k0 + bKg * 8) * DIN;
      #pragma unroll
      for (int c = 0; c < 4; c++) {
        const int n = bA + 32 * c;
        const float* s = srow + n;
        u16x8 pk;
        #pragma unroll
        for (int r = 0; r < 8; r++) pk[r] = f2b(s[(size_t)r * DIN]);
        *(u16x8*)&Bs[n * LDK + bKg * 8] = pk;
      }
    }
    __syncthreads();
    u16x8 af[4];
    #pragma unroll
    for (int fm = 0; fm < 4; fm++)
      af[fm] = *(const u16x8*)&As[(wr * 64 + fm * 16 + mrow) * LDK + krow];
    #pragma unroll
    for (int fn = 0; fn < 4; fn++) {
      u16x8 bf = *(const u16x8*)&Bs[(wc * 64 + fn * 16 + mrow) * LDK + krow];
      #pragma unroll
      for (int fm = 0; fm < 4; fm++)
        acc[fm][fn] = __builtin_amdgcn_mfma_f32_16x16x32_bf16(
            __builtin_bit_cast(bf16x8, af[fm]), __builtin_bit_cast(bf16x8, bf),
            acc[fm][fn], 0, 0, 0);
    }
    __syncthreads();
  }
  #pragma unroll
  for (int fm = 0; fm < 4; fm++) {
    const int rbase = row0 + wr * 64 + fm * 16 + (lane >> 4) * 4;
    #pragma unroll
    for (int fn = 0; fn < 4; fn++) {
      const int col = n0 + wc * 64 + fn * 16 + mrow;
      #pragma unroll
      for (int j = 0; j < 4; j++) {
        const int t = perm[rbase + j];
        if (t >= 0) out[(size_t)t * DIN + col] = acc[fm][fn][j];
      }
    }
  }
}

extern "C" void kernel_launch(void* const* d_in, const int* in_sizes, int n_in,
                              void* d_out, int out_size, void* d_ws, size_t ws_size,
                              hipStream_t stream) {
  const float* x        = (const float*)d_in[0];
  const float* w_router = (const float*)d_in[1];
  const float* w_v      = (const float*)d_in[2];
  const float* w_proj   = (const float*)d_in[3];
  float* out = (float*)d_out;
  char* ws = (char*)d_ws;

  int* cnt  = (int*)(ws + 0);      // 4
  int* nMt  = (int*)(ws + 16);     // 1
  int* poff = (int*)(ws + 32);     // 5
  int* tExp = (int*)(ws + 128);    // <=40
  int* tRow = (int*)(ws + 320);    // <=40
  int* eidx = (int*)(ws + 512);            // 4096
  int* rank = (int*)(ws + 512 + 16384);    // 4096
  int* perm = (int*)(ws + 512 + 32768);    // 4608, ends 51712
  unsigned short* Abuf = (unsigned short*)(ws + 52224);            // 4608x1024 bf16
  unsigned short* Hbuf = (unsigned short*)(ws + 52224 + 9437184);  // 4608x4096 bf16

  hipMemsetAsync(cnt, 0, 16, stream);
  hipMemsetAsync(perm, 0xFF, TPAD * 4, stream);  // perm = -1 (pad sentinel)
  k_router<<<TTOK / 4, 256, 0, stream>>>(x, w_router, eidx, rank, cnt);
  k_setup<<<1, 1, 0, stream>>>(cnt, poff, tExp, tRow, nMt);
  k_scatter<<<TTOK / 256, 256, 0, stream>>>(eidx, rank, poff, perm);
  k_gather<<<TPAD, 256, 0, stream>>>(x, perm, Abuf);
  k_gemm1<<<dim3(HDIM / 128, 36), 256, 0, stream>>>(Abuf, w_v, Hbuf, tExp, tRow, nMt);
  k_gemm2<<<dim3(DIN / 128, 36), 256, 0, stream>>>(Hbuf, w_proj, out, tExp, tRow, nMt, perm);
}

// Round 2
// 599.477 us; speedup vs baseline: 1.1437x; 1.1437x over previous
//
#include <hip/hip_runtime.h>

// MoE top-1 + SwiGLU. B=2 S=2048 D=1024 E=4 H=4096.
// Round 2: pre-convert+transpose weights to bf16 [n][k] once, then
// m97-style GEMMs (global_load_lds w16, linear [128][32] LDS, 2-barrier loop).
// GEMM1 fuses SiLU(g)*v; GEMM2 split-K=2 with fp32 atomicAdd scatter.

#define TTOK 4096
#define DIN  1024
#define HDIM 4096
#define H2   8192
#define TPAD 4608

typedef float f32x4 __attribute__((ext_vector_type(4)));
typedef __bf16 bf16x8 __attribute__((ext_vector_type(8)));
typedef unsigned short u16x8 __attribute__((ext_vector_type(8)));
typedef unsigned short u16x4 __attribute__((ext_vector_type(4)));

__device__ __forceinline__ unsigned short f2b(float f) {
  unsigned int u = __builtin_bit_cast(unsigned int, f);
  u += 0x7fffu + ((u >> 16) & 1u);  // RNE
  return (unsigned short)(u >> 16);
}

// async global->LDS, 16B per lane; LDS dest must be wave-uniform base.
__device__ __forceinline__ void gload16(const void* g, void* l) {
  __builtin_amdgcn_global_load_lds(
      (const __attribute__((address_space(1))) unsigned int*)g,
      (__attribute__((address_space(3))) unsigned int*)l, 16, 0, 0);
}

// ---------------- router: logits argmax + histogram ----------------
__global__ __launch_bounds__(256) void k_router(const float* __restrict__ x,
    const float* __restrict__ wrt, int* __restrict__ eidx,
    int* __restrict__ rank, int* __restrict__ cnt) {
  const int w = threadIdx.x >> 6, lane = threadIdx.x & 63;
  const int t = blockIdx.x * 4 + w;
  const float* xr = x + (size_t)t * DIN;
  const float4* w4 = (const float4*)wrt;  // w_router[k][e], e fastest
  float a0 = 0.f, a1 = 0.f, a2 = 0.f, a3 = 0.f;
  for (int k = 0; k < DIN; k += 64) {
    float xv = xr[k + lane];
    float4 ww = w4[k + lane];
    a0 += xv * ww.x; a1 += xv * ww.y; a2 += xv * ww.z; a3 += xv * ww.w;
  }
  #pragma unroll
  for (int off = 32; off; off >>= 1) {
    a0 += __shfl_xor(a0, off); a1 += __shfl_xor(a1, off);
    a2 += __shfl_xor(a2, off); a3 += __shfl_xor(a3, off);
  }
  if (lane == 0) {
    int e = 0; float b = a0;
    if (a1 > b) { b = a1; e = 1; }
    if (a2 > b) { b = a2; e = 2; }
    if (a3 > b) { b = a3; e = 3; }
    eidx[t] = e;
    rank[t] = atomicAdd(&cnt[e], 1);
  }
}

// ---------------- setup: padded segment offsets + M-tile table ----------------
__global__ void k_setup(const int* __restrict__ cnt, int* __restrict__ poff,
                        int* __restrict__ tExp, int* __restrict__ tRow,
                        int* __restrict__ nMt) {
  int p = 0, nm = 0;
  for (int e = 0; e < 4; e++) {
    poff[e] = p;
    int mt = (cnt[e] + 127) >> 7;
    for (int i = 0; i < mt; i++) { tExp[nm] = e; tRow[nm] = p + i * 128; nm++; }
    p += mt * 128;
  }
  poff[4] = p;
  *nMt = nm;
}

// ---------------- scatter: token -> sorted padded slot ----------------
__global__ __launch_bounds__(256) void k_scatter(const int* __restrict__ eidx,
    const int* __restrict__ rank, const int* __restrict__ poff,
    int* __restrict__ perm) {
  const int t = blockIdx.x * 256 + threadIdx.x;
  const int pos = poff[eidx[t]] + rank[t];
  perm[pos] = t;
}

// ---------------- gather x rows to bf16 A matrix (pads -> 0) ----------------
__global__ __launch_bounds__(256) void k_gather(const float* __restrict__ x,
    const int* __restrict__ perm, unsigned short* __restrict__ A) {
  const int r = blockIdx.x;
  const int t = perm[r];
  unsigned short* dst = A + (size_t)r * DIN + threadIdx.x * 4;
  if (t < 0) {
    u16x4 z{0, 0, 0, 0};
    *(u16x4*)dst = z;
  } else {
    float4 v = *(const float4*)(x + (size_t)t * DIN + threadIdx.x * 4);
    u16x4 o{f2b(v.x), f2b(v.y), f2b(v.z), f2b(v.w)};
    *(u16x4*)dst = o;
  }
}

// ---------------- transpose+cvt: src fp32 [E][K][N] -> dst bf16 [E][N][K] ----------------
// grid (N/64, K/64, E), 256 threads, 64x64 tile via LDS.
__global__ __launch_bounds__(256) void k_transpose(const float* __restrict__ src,
    unsigned short* __restrict__ dst, int K, int N) {
  __shared__ __align__(16) unsigned short T[64][72];  // 144B row stride, 16B-aligned
  const int n0 = blockIdx.x * 64, k0 = blockIdx.y * 64;
  const size_t eoff = (size_t)blockIdx.z * K * N;
  const int tid = threadIdx.x;
  const int rr = tid >> 4;         // 0..15
  const int cc = (tid & 15) * 4;   // 0..60
  #pragma unroll
  for (int i = 0; i < 4; i++) {
    const int r = rr + i * 16;  // k within tile
    float4 v = *(const float4*)(src + eoff + (size_t)(k0 + r) * N + n0 + cc);
    T[cc + 0][r] = f2b(v.x);
    T[cc + 1][r] = f2b(v.y);
    T[cc + 2][r] = f2b(v.z);
    T[cc + 3][r] = f2b(v.w);
  }
  __syncthreads();
  const int n = tid >> 2, kc = (tid & 3) * 16;
  u16x8 a = *(const u16x8*)&T[n][kc];
  u16x8 b = *(const u16x8*)&T[n][kc + 8];
  unsigned short* dp = dst + eoff + (size_t)(n0 + n) * K + k0 + kc;
  *(u16x8*)(dp) = a;
  *(u16x8*)(dp + 8) = b;
}

// ---------------- GEMM1: A[128xK] @ Wvt -> fused SwiGLU -> h bf16 ----------------
// Block: 128 rows x 128 gate cols + paired 128 value cols. Wvt bf16 [E][8192][1024].
__global__ __launch_bounds__(256) void k_gemm1(const unsigned short* __restrict__ A,
    const unsigned short* __restrict__ Wt, unsigned short* __restrict__ Hb,
    const int* __restrict__ tExp, const int* __restrict__ tRow,
    const int* __restrict__ nMt) {
  if ((int)blockIdx.y >= *nMt) return;
  __shared__ __align__(16) unsigned short As[128 * 32];
  __shared__ __align__(16) unsigned short Bg[128 * 32];
  __shared__ __align__(16) unsigned short Bv[128 * 32];
  const int e = tExp[blockIdx.y];
  const int row0 = tRow[blockIdx.y];
  const int n0 = blockIdx.x * 128;
  const int tid = threadIdx.x, lane = tid & 63;
  const int w = tid >> 6, wr = w >> 1, wc = w & 1;
  const int rl = lane >> 2;        // row within 16-row segment
  const int kc = (lane & 3) * 8;   // k chunk (elems)
  const int mrow = lane & 15, krow = (lane >> 4) * 8;

  const unsigned short* aG  = A  + (size_t)(row0 + w * 16 + rl) * DIN + kc;
  const unsigned short* bgG = Wt + (size_t)e * H2 * DIN
                                 + (size_t)(n0 + w * 16 + rl) * DIN + kc;
  const unsigned short* bvG = bgG + (size_t)HDIM * DIN;

  f32x4 accg[4][4], accv[4][4];
  #pragma unroll
  for (int i = 0; i < 4; i++)
    #pragma unroll
    for (int j = 0; j < 4; j++) {
      accg[i][j] = f32x4{0.f, 0.f, 0.f, 0.f};
      accv[i][j] = f32x4{0.f, 0.f, 0.f, 0.f};
    }

  for (int k0 = 0; k0 < DIN; k0 += 32) {
    gload16(aG + k0,                     &As[w * 512]);
    gload16(aG + k0 + (size_t)64 * DIN,  &As[w * 512 + 2048]);
    gload16(bgG + k0,                    &Bg[w * 512]);
    gload16(bgG + k0 + (size_t)64 * DIN, &Bg[w * 512 + 2048]);
    gload16(bvG + k0,                    &Bv[w * 512]);
    gload16(bvG + k0 + (size_t)64 * DIN, &Bv[w * 512 + 2048]);
    __syncthreads();
    u16x8 af[4], bg[4], bv[4];
    #pragma unroll
    for (int f = 0; f < 4; f++) {
      af[f] = *(const u16x8*)&As[(wr * 64 + f * 16 + mrow) * 32 + krow];
      bg[f] = *(const u16x8*)&Bg[(wc * 64 + f * 16 + mrow) * 32 + krow];
      bv[f] = *(const u16x8*)&Bv[(wc * 64 + f * 16 + mrow) * 32 + krow];
    }
    #pragma unroll
    for (int fn = 0; fn < 4; fn++)
      #pragma unroll
      for (int fm = 0; fm < 4; fm++) {
        accg[fm][fn] = __builtin_amdgcn_mfma_f32_16x16x32_bf16(
            __builtin_bit_cast(bf16x8, af[fm]), __builtin_bit_cast(bf16x8, bg[fn]),
            accg[fm][fn], 0, 0, 0);
        accv[fm][fn] = __builtin_amdgcn_mfma_f32_16x16x32_bf16(
            __builtin_bit_cast(bf16x8, af[fm]), __builtin_bit_cast(bf16x8, bv[fn]),
            accv[fm][fn], 0, 0, 0);
      }
    __syncthreads();
  }
  // epilogue: h = silu(g)*v, store bf16
  #pragma unroll
  for (int fm = 0; fm < 4; fm++) {
    const int rbase = row0 + wr * 64 + fm * 16 + (lane >> 4) * 4;
    #pragma unroll
    for (int fn = 0; fn < 4; fn++) {
      const int col = n0 + wc * 64 + fn * 16 + mrow;
      #pragma unroll
      for (int j = 0; j < 4; j++) {
        float g = accg[fm][fn][j];
        float v = accv[fm][fn][j];
        float h = g / (1.f + __expf(-g)) * v;
        Hb[(size_t)(rbase + j) * HDIM + col] = f2b(h);
      }
    }
  }
}

// ---------------- GEMM2: h @ Wpt (split-K=2) -> atomicAdd scatter fp32 out ----------------
// Wpt bf16 [E][1024][4096]. grid (DIN/128, 2*36): y = mtile*2 + ksplit.
__global__ __launch_bounds__(256) void k_gemm2(const unsigned short* __restrict__ Hb,
    const unsigned short* __restrict__ Wt, float* __restrict__ out,
    const int* __restrict__ tExp, const int* __restrict__ tRow,
    const int* __restrict__ nMt, const int* __restrict__ perm) {
  const int my = blockIdx.y >> 1;
  const int ks = blockIdx.y & 1;
  if (my >= *nMt) return;
  __shared__ __align__(16) unsigned short As[128 * 32];
  __shared__ __align__(16) unsigned short Bs[128 * 32];
  const int e = tExp[my];
  const int row0 = tRow[my];
  const int n0 = blockIdx.x * 128;
  const int tid = threadIdx.x, lane = tid & 63;
  const int w = tid >> 6, wr = w >> 1, wc = w & 1;
  const int rl = lane >> 2, kc = (lane & 3) * 8;
  const int mrow = lane & 15, krow = (lane >> 4) * 8;

  const unsigned short* aG = Hb + (size_t)(row0 + w * 16 + rl) * HDIM + ks * 2048 + kc;
  const unsigned short* bG = Wt + (size_t)e * DIN * HDIM
                                + (size_t)(n0 + w * 16 + rl) * HDIM + ks * 2048 + kc;
  f32x4 acc[4][4];
  #pragma unroll
  for (int i = 0; i < 4; i++)
    #pragma unroll
    for (int j = 0; j < 4; j++) acc[i][j] = f32x4{0.f, 0.f, 0.f, 0.f};

  for (int k0 = 0; k0 < 2048; k0 += 32) {
    gload16(aG + k0,                      &As[w * 512]);
    gload16(aG + k0 + (size_t)64 * HDIM,  &As[w * 512 + 2048]);
    gload16(bG + k0,                      &Bs[w * 512]);
    gload16(bG + k0 + (size_t)64 * HDIM,  &Bs[w * 512 + 2048]);
    __syncthreads();
    u16x8 af[4], bf[4];
    #pragma unroll
    for (int f = 0; f < 4; f++) {
      af[f] = *(const u16x8*)&As[(wr * 64 + f * 16 + mrow) * 32 + krow];
      bf[f] = *(const u16x8*)&Bs[(wc * 64 + f * 16 + mrow) * 32 + krow];
    }
    #pragma unroll
    for (int fn = 0; fn < 4; fn++)
      #pragma unroll
      for (int fm = 0; fm < 4; fm++)
        acc[fm][fn] = __builtin_amdgcn_mfma_f32_16x16x32_bf16(
            __builtin_bit_cast(bf16x8, af[fm]), __builtin_bit_cast(bf16x8, bf[fn]),
            acc[fm][fn], 0, 0, 0);
    __syncthreads();
  }
  #pragma unroll
  for (int fm = 0; fm < 4; fm++) {
    const int rbase = row0 + wr * 64 + fm * 16 + (lane >> 4) * 4;
    #pragma unroll
    for (int fn = 0; fn < 4; fn++) {
      const int col = n0 + wc * 64 + fn * 16 + mrow;
      #pragma unroll
      for (int j = 0; j < 4; j++) {
        const int t = perm[rbase + j];
        if (t >= 0) atomicAdd(&out[(size_t)t * DIN + col], acc[fm][fn][j]);
      }
    }
  }
}

extern "C" void kernel_launch(void* const* d_in, const int* in_sizes, int n_in,
                              void* d_out, int out_size, void* d_ws, size_t ws_size,
                              hipStream_t stream) {
  const float* x        = (const float*)d_in[0];
  const float* w_router = (const float*)d_in[1];
  const float* w_v      = (const float*)d_in[2];
  const float* w_proj   = (const float*)d_in[3];
  float* out = (float*)d_out;
  char* ws = (char*)d_ws;

  int* cnt  = (int*)(ws + 0);
  int* nMt  = (int*)(ws + 16);
  int* poff = (int*)(ws + 32);
  int* tExp = (int*)(ws + 128);
  int* tRow = (int*)(ws + 320);
  int* eidx = (int*)(ws + 512);
  int* rank = (int*)(ws + 512 + 16384);
  int* perm = (int*)(ws + 512 + 32768);
  unsigned short* Abuf = (unsigned short*)(ws + 52224);              // 4608x1024 bf16
  unsigned short* Hbuf = (unsigned short*)(ws + 9489408);            // 4608x4096 bf16
  unsigned short* Wvt  = (unsigned short*)(ws + 47238144);           // 4x8192x1024 bf16
  unsigned short* Wpt  = (unsigned short*)(ws + 114347008);          // 4x1024x4096 bf16
  // total ws use: 147,901,440 B

  hipMemsetAsync(cnt, 0, 16, stream);
  hipMemsetAsync(perm, 0xFF, TPAD * 4, stream);
  hipMemsetAsync(out, 0, (size_t)out_size * 4, stream);
  k_router<<<TTOK / 4, 256, 0, stream>>>(x, w_router, eidx, rank, cnt);
  k_setup<<<1, 1, 0, stream>>>(cnt, poff, tExp, tRow, nMt);
  k_scatter<<<TTOK / 256, 256, 0, stream>>>(eidx, rank, poff, perm);
  k_gather<<<TPAD, 256, 0, stream>>>(x, perm, Abuf);
  k_transpose<<<dim3(H2 / 64, DIN / 64, 4), 256, 0, stream>>>(w_v, Wvt, DIN, H2);
  k_transpose<<<dim3(DIN / 64, HDIM / 64, 4), 256, 0, stream>>>(w_proj, Wpt, HDIM, DIN);
  k_gemm1<<<dim3(HDIM / 128, 36), 256, 0, stream>>>(Abuf, Wvt, Hbuf, tExp, tRow, nMt);
  k_gemm2<<<dim3(DIN / 128, 72), 256, 0, stream>>>(Hbuf, Wpt, out, tExp, tRow, nMt, perm);
}

// Round 3
// 594.180 us; speedup vs baseline: 1.1539x; 1.0089x over previous
//
#include <hip/hip_runtime.h>

// MoE top-1 + SwiGLU. B=2 S=2048 D=1024 E=4 H=4096.
// Round 3: 2-phase prefetch GEMMs (double-buffered LDS, stage(t+1) issued
// before compute(t), ONE barrier per K-step). Weights pre-transposed to
// bf16 [n][k] once. GEMM1 fuses SiLU(g)*v; GEMM2 split-K=2 + atomicAdd.

#define TTOK 4096
#define DIN  1024
#define HDIM 4096
#define H2   8192
#define TPAD 4608

typedef float f32x4 __attribute__((ext_vector_type(4)));
typedef __bf16 bf16x8 __attribute__((ext_vector_type(8)));
typedef unsigned short u16x8 __attribute__((ext_vector_type(8)));
typedef unsigned short u16x4 __attribute__((ext_vector_type(4)));

__device__ __forceinline__ unsigned short f2b(float f) {
  unsigned int u = __builtin_bit_cast(unsigned int, f);
  u += 0x7fffu + ((u >> 16) & 1u);  // RNE
  return (unsigned short)(u >> 16);
}

// async global->LDS, 16B per lane; LDS dest is wave-uniform base + lane*16B.
__device__ __forceinline__ void gload16(const void* g, void* l) {
  __builtin_amdgcn_global_load_lds(
      (const __attribute__((address_space(1))) unsigned int*)g,
      (__attribute__((address_space(3))) unsigned int*)l, 16, 0, 0);
}

// ---------------- router: logits argmax + histogram ----------------
__global__ __launch_bounds__(256) void k_router(const float* __restrict__ x,
    const float* __restrict__ wrt, int* __restrict__ eidx,
    int* __restrict__ rank, int* __restrict__ cnt) {
  const int w = threadIdx.x >> 6, lane = threadIdx.x & 63;
  const int t = blockIdx.x * 4 + w;
  const float* xr = x + (size_t)t * DIN;
  const float4* w4 = (const float4*)wrt;  // w_router[k][e], e fastest
  float a0 = 0.f, a1 = 0.f, a2 = 0.f, a3 = 0.f;
  for (int k = 0; k < DIN; k += 64) {
    float xv = xr[k + lane];
    float4 ww = w4[k + lane];
    a0 += xv * ww.x; a1 += xv * ww.y; a2 += xv * ww.z; a3 += xv * ww.w;
  }
  #pragma unroll
  for (int off = 32; off; off >>= 1) {
    a0 += __shfl_xor(a0, off); a1 += __shfl_xor(a1, off);
    a2 += __shfl_xor(a2, off); a3 += __shfl_xor(a3, off);
  }
  if (lane == 0) {
    int e = 0; float b = a0;
    if (a1 > b) { b = a1; e = 1; }
    if (a2 > b) { b = a2; e = 2; }
    if (a3 > b) { b = a3; e = 3; }
    eidx[t] = e;
    rank[t] = atomicAdd(&cnt[e], 1);
  }
}

// ---------------- setup: padded segment offsets + M-tile table ----------------
__global__ void k_setup(const int* __restrict__ cnt, int* __restrict__ poff,
                        int* __restrict__ tExp, int* __restrict__ tRow,
                        int* __restrict__ nMt) {
  int p = 0, nm = 0;
  for (int e = 0; e < 4; e++) {
    poff[e] = p;
    int mt = (cnt[e] + 127) >> 7;
    for (int i = 0; i < mt; i++) { tExp[nm] = e; tRow[nm] = p + i * 128; nm++; }
    p += mt * 128;
  }
  poff[4] = p;
  *nMt = nm;
}

// ---------------- scatter: token -> sorted padded slot ----------------
__global__ __launch_bounds__(256) void k_scatter(const int* __restrict__ eidx,
    const int* __restrict__ rank, const int* __restrict__ poff,
    int* __restrict__ perm) {
  const int t = blockIdx.x * 256 + threadIdx.x;
  const int pos = poff[eidx[t]] + rank[t];
  perm[pos] = t;
}

// ---------------- gather x rows to bf16 A matrix (pads -> 0) ----------------
__global__ __launch_bounds__(256) void k_gather(const float* __restrict__ x,
    const int* __restrict__ perm, unsigned short* __restrict__ A) {
  const int r = blockIdx.x;
  const int t = perm[r];
  unsigned short* dst = A + (size_t)r * DIN + threadIdx.x * 4;
  if (t < 0) {
    u16x4 z{0, 0, 0, 0};
    *(u16x4*)dst = z;
  } else {
    float4 v = *(const float4*)(x + (size_t)t * DIN + threadIdx.x * 4);
    u16x4 o{f2b(v.x), f2b(v.y), f2b(v.z), f2b(v.w)};
    *(u16x4*)dst = o;
  }
}

// ---------------- transpose+cvt: src fp32 [E][K][N] -> dst bf16 [E][N][K] ----------------
__global__ __launch_bounds__(256) void k_transpose(const float* __restrict__ src,
    unsigned short* __restrict__ dst, int K, int N) {
  __shared__ __align__(16) unsigned short T[64][72];
  const int n0 = blockIdx.x * 64, k0 = blockIdx.y * 64;
  const size_t eoff = (size_t)blockIdx.z * K * N;
  const int tid = threadIdx.x;
  const int rr = tid >> 4;
  const int cc = (tid & 15) * 4;
  #pragma unroll
  for (int i = 0; i < 4; i++) {
    const int r = rr + i * 16;
    float4 v = *(const float4*)(src + eoff + (size_t)(k0 + r) * N + n0 + cc);
    T[cc + 0][r] = f2b(v.x);
    T[cc + 1][r] = f2b(v.y);
    T[cc + 2][r] = f2b(v.z);
    T[cc + 3][r] = f2b(v.w);
  }
  __syncthreads();
  const int n = tid >> 2, kc = (tid & 3) * 16;
  u16x8 a = *(const u16x8*)&T[n][kc];
  u16x8 b = *(const u16x8*)&T[n][kc + 8];
  unsigned short* dp = dst + eoff + (size_t)(n0 + n) * K + k0 + kc;
  *(u16x8*)(dp) = a;
  *(u16x8*)(dp + 8) = b;
}

// ---------------- GEMM1: A[128xK] @ Wvt -> fused SwiGLU -> h bf16 ----------------
// 2-phase prefetch: stage(t+1) issued before compute(t); one barrier/K-step.
__global__ __launch_bounds__(256) void k_gemm1(const unsigned short* __restrict__ A,
    const unsigned short* __restrict__ Wt, unsigned short* __restrict__ Hb,
    const int* __restrict__ tExp, const int* __restrict__ tRow,
    const int* __restrict__ nMt) {
  if ((int)blockIdx.y >= *nMt) return;
  __shared__ __align__(16) unsigned short As[2][128 * 32];
  __shared__ __align__(16) unsigned short Bg[2][128 * 32];
  __shared__ __align__(16) unsigned short Bv[2][128 * 32];
  const int e = tExp[blockIdx.y];
  const int row0 = tRow[blockIdx.y];
  const int n0 = blockIdx.x * 128;
  const int tid = threadIdx.x, lane = tid & 63;
  const int w = tid >> 6, wr = w >> 1, wc = w & 1;
  const int rl = lane >> 2;        // row within 16-row segment
  const int kc = (lane & 3) * 8;   // k chunk (elems)
  const int mrow = lane & 15, krow = (lane >> 4) * 8;

  const unsigned short* aG  = A  + (size_t)(row0 + w * 16 + rl) * DIN + kc;
  const unsigned short* bgG = Wt + (size_t)e * H2 * DIN
                                 + (size_t)(n0 + w * 16 + rl) * DIN + kc;
  const unsigned short* bvG = bgG + (size_t)HDIM * DIN;
  const int ldst = w * 512;  // wave-uniform LDS dest offset (u16 elems)

  f32x4 accg[4][4], accv[4][4];
  #pragma unroll
  for (int i = 0; i < 4; i++)
    #pragma unroll
    for (int j = 0; j < 4; j++) {
      accg[i][j] = f32x4{0.f, 0.f, 0.f, 0.f};
      accv[i][j] = f32x4{0.f, 0.f, 0.f, 0.f};
    }

  auto STAGE = [&](int b, int k0) {
    gload16(aG + k0,                     &As[b][ldst]);
    gload16(aG + k0 + (size_t)64 * DIN,  &As[b][ldst + 2048]);
    gload16(bgG + k0,                    &Bg[b][ldst]);
    gload16(bgG + k0 + (size_t)64 * DIN, &Bg[b][ldst + 2048]);
    gload16(bvG + k0,                    &Bv[b][ldst]);
    gload16(bvG + k0 + (size_t)64 * DIN, &Bv[b][ldst + 2048]);
  };

  STAGE(0, 0);
  __syncthreads();
  int cur = 0;
  for (int k0 = 0; k0 < DIN; k0 += 32) {
    if (k0 + 32 < DIN) STAGE(cur ^ 1, k0 + 32);  // prefetch flies under MFMA
    u16x8 af[4], bg[4], bv[4];
    #pragma unroll
    for (int f = 0; f < 4; f++) {
      af[f] = *(const u16x8*)&As[cur][(wr * 64 + f * 16 + mrow) * 32 + krow];
      bg[f] = *(const u16x8*)&Bg[cur][(wc * 64 + f * 16 + mrow) * 32 + krow];
      bv[f] = *(const u16x8*)&Bv[cur][(wc * 64 + f * 16 + mrow) * 32 + krow];
    }
    #pragma unroll
    for (int fn = 0; fn < 4; fn++)
      #pragma unroll
      for (int fm = 0; fm < 4; fm++) {
        accg[fm][fn] = __builtin_amdgcn_mfma_f32_16x16x32_bf16(
            __builtin_bit_cast(bf16x8, af[fm]), __builtin_bit_cast(bf16x8, bg[fn]),
            accg[fm][fn], 0, 0, 0);
        accv[fm][fn] = __builtin_amdgcn_mfma_f32_16x16x32_bf16(
            __builtin_bit_cast(bf16x8, af[fm]), __builtin_bit_cast(bf16x8, bv[fn]),
            accv[fm][fn], 0, 0, 0);
      }
    __syncthreads();  // drains prefetch (vmcnt0) + protects buffer swap
    cur ^= 1;
  }
  // epilogue: h = silu(g)*v, store bf16
  #pragma unroll
  for (int fm = 0; fm < 4; fm++) {
    const int rbase = row0 + wr * 64 + fm * 16 + (lane >> 4) * 4;
    #pragma unroll
    for (int fn = 0; fn < 4; fn++) {
      const int col = n0 + wc * 64 + fn * 16 + mrow;
      #pragma unroll
      for (int j = 0; j < 4; j++) {
        float g = accg[fm][fn][j];
        float v = accv[fm][fn][j];
        float h = g / (1.f + __expf(-g)) * v;
        Hb[(size_t)(rbase + j) * HDIM + col] = f2b(h);
      }
    }
  }
}

// ---------------- GEMM2: h @ Wpt (split-K=2) -> atomicAdd scatter fp32 out ----------------
__global__ __launch_bounds__(256) void k_gemm2(const unsigned short* __restrict__ Hb,
    const unsigned short* __restrict__ Wt, float* __restrict__ out,
    const int* __restrict__ tExp, const int* __restrict__ tRow,
    const int* __restrict__ nMt, const int* __restrict__ perm) {
  const int my = blockIdx.y >> 1;
  const int ks = blockIdx.y & 1;
  if (my >= *nMt) return;
  __shared__ __align__(16) unsigned short As[2][128 * 32];
  __shared__ __align__(16) unsigned short Bs[2][128 * 32];
  const int e = tExp[my];
  const int row0 = tRow[my];
  const int n0 = blockIdx.x * 128;
  const int tid = threadIdx.x, lane = tid & 63;
  const int w = tid >> 6, wr = w >> 1, wc = w & 1;
  const int rl = lane >> 2, kc = (lane & 3) * 8;
  const int mrow = lane & 15, krow = (lane >> 4) * 8;

  const unsigned short* aG = Hb + (size_t)(row0 + w * 16 + rl) * HDIM + ks * 2048 + kc;
  const unsigned short* bG = Wt + (size_t)e * DIN * HDIM
                                + (size_t)(n0 + w * 16 + rl) * HDIM + ks * 2048 + kc;
  const int ldst = w * 512;
  f32x4 acc[4][4];
  #pragma unroll
  for (int i = 0; i < 4; i++)
    #pragma unroll
    for (int j = 0; j < 4; j++) acc[i][j] = f32x4{0.f, 0.f, 0.f, 0.f};

  auto STAGE = [&](int b, int k0) {
    gload16(aG + k0,                      &As[b][ldst]);
    gload16(aG + k0 + (size_t)64 * HDIM,  &As[b][ldst + 2048]);
    gload16(bG + k0,                      &Bs[b][ldst]);
    gload16(bG + k0 + (size_t)64 * HDIM,  &Bs[b][ldst + 2048]);
  };

  STAGE(0, 0);
  __syncthreads();
  int cur = 0;
  for (int k0 = 0; k0 < 2048; k0 += 32) {
    if (k0 + 32 < 2048) STAGE(cur ^ 1, k0 + 32);
    u16x8 af[4], bf[4];
    #pragma unroll
    for (int f = 0; f < 4; f++) {
      af[f] = *(const u16x8*)&As[cur][(wr * 64 + f * 16 + mrow) * 32 + krow];
      bf[f] = *(const u16x8*)&Bs[cur][(wc * 64 + f * 16 + mrow) * 32 + krow];
    }
    #pragma unroll
    for (int fn = 0; fn < 4; fn++)
      #pragma unroll
      for (int fm = 0; fm < 4; fm++)
        acc[fm][fn] = __builtin_amdgcn_mfma_f32_16x16x32_bf16(
            __builtin_bit_cast(bf16x8, af[fm]), __builtin_bit_cast(bf16x8, bf[fn]),
            acc[fm][fn], 0, 0, 0);
    __syncthreads();
    cur ^= 1;
  }
  #pragma unroll
  for (int fm = 0; fm < 4; fm++) {
    const int rbase = row0 + wr * 64 + fm * 16 + (lane >> 4) * 4;
    #pragma unroll
    for (int fn = 0; fn < 4; fn++) {
      const int col = n0 + wc * 64 + fn * 16 + mrow;
      #pragma unroll
      for (int j = 0; j < 4; j++) {
        const int t = perm[rbase + j];
        if (t >= 0) atomicAdd(&out[(size_t)t * DIN + col], acc[fm][fn][j]);
      }
    }
  }
}

extern "C" void kernel_launch(void* const* d_in, const int* in_sizes, int n_in,
                              void* d_out, int out_size, void* d_ws, size_t ws_size,
                              hipStream_t stream) {
  const float* x        = (const float*)d_in[0];
  const float* w_router = (const float*)d_in[1];
  const float* w_v      = (const float*)d_in[2];
  const float* w_proj   = (const float*)d_in[3];
  float* out = (float*)d_out;
  char* ws = (char*)d_ws;

  int* cnt  = (int*)(ws + 0);
  int* nMt  = (int*)(ws + 16);
  int* poff = (int*)(ws + 32);
  int* tExp = (int*)(ws + 128);
  int* tRow = (int*)(ws + 320);
  int* eidx = (int*)(ws + 512);
  int* rank = (int*)(ws + 512 + 16384);
  int* perm = (int*)(ws + 512 + 32768);
  unsigned short* Abuf = (unsigned short*)(ws + 52224);              // 4608x1024 bf16
  unsigned short* Hbuf = (unsigned short*)(ws + 9489408);            // 4608x4096 bf16
  unsigned short* Wvt  = (unsigned short*)(ws + 47238144);           // 4x8192x1024 bf16
  unsigned short* Wpt  = (unsigned short*)(ws + 114347008);          // 4x1024x4096 bf16

  hipMemsetAsync(cnt, 0, 16, stream);
  hipMemsetAsync(perm, 0xFF, TPAD * 4, stream);
  hipMemsetAsync(out, 0, (size_t)out_size * 4, stream);
  k_router<<<TTOK / 4, 256, 0, stream>>>(x, w_router, eidx, rank, cnt);
  k_setup<<<1, 1, 0, stream>>>(cnt, poff, tExp, tRow, nMt);
  k_scatter<<<TTOK / 256, 256, 0, stream>>>(eidx, rank, poff, perm);
  k_gather<<<TPAD, 256, 0, stream>>>(x, perm, Abuf);
  k_transpose<<<dim3(H2 / 64, DIN / 64, 4), 256, 0, stream>>>(w_v, Wvt, DIN, H2);
  k_transpose<<<dim3(DIN / 64, HDIM / 64, 4), 256, 0, stream>>>(w_proj, Wpt, HDIM, DIN);
  k_gemm1<<<dim3(HDIM / 128, 36), 256, 0, stream>>>(Abuf, Wvt, Hbuf, tExp, tRow, nMt);
  k_gemm2<<<dim3(DIN / 128, 72), 256, 0, stream>>>(Hbuf, Wpt, out, tExp, tRow, nMt, perm);
}